// Round 3
// baseline (81.236 us; speedup 1.0000x reference)
//
#include <hip/hip_runtime.h>

// AliasFreeActivation, round 3: band-per-block, down-v in registers.
// x (2,256,84,84) f32 -> up x4 (24t sep) -> lrelu -> down x2 (12t sep) -> crop 10
// out (2,256,148,148) f32.
//
// out[i][j] = sum_u kd[u] * tv[i][2j+26-u],  tv[i][c] = sum_s kd[s] * z[2i+26-s][c]
// z rows/cols needed: [15,320] -> all x taps in-bounds, NO boundary checks.
// Band b: out rows i0=32b..i0+NROWS-1; z rows ZR0=2*i0+15 (ZR0 % 4 == 3 always),
// NZR=2*NROWS+10; input rows IR0=16b+1, NIR rows; z cols 15..320 (306, local zc).

constexpr int IN_HW  = 84;
constexpr int OUT_HW = 148;
constexpr int NCOL   = 306;   // local z columns
constexpr int STR    = 356;   // dword row stride for s_uph / s_tv (skewed cols)
constexpr int UPH_OFF = 2016; // s_in = 24*84 dwords
constexpr int LDS_DW  = 32 * STR;  // 11392 dw = 45568 B (union: in+uph | tv)
constexpr float SLOPE = 0.2f;

__device__ __forceinline__ float rfl(float v) {
    return __uint_as_float(__builtin_amdgcn_readfirstlane(__float_as_uint(v)));
}

template<int NROWS, int NZR, int NIR>
__device__ __forceinline__ void band_body(
    const float* __restrict__ xin, float* __restrict__ o,
    const float* fu, const float* fd, float* sbuf, int tid, int band)
{
    float* s_in  = sbuf;             // [NIR][84], cols = x cols 1..82
    float* s_uph = sbuf + UPH_OFF;   // [NIR][STR], skewed cols
    float* s_tv  = sbuf;             // [NROWS][STR] (aliases; written post-sync)

    const int i0  = 32 * band;
    const int IR0 = 16 * band + 1;

    // ---- P0: stage input (always in-bounds) ----
    for (unsigned e = tid; e < NIR * 82u; e += 320) {
        unsigned r = e / 82u, c = e - r * 82u;
        s_in[r * 84 + c] = xin[(IR0 + r) * IN_HW + 1 + c];
    }
    __syncthreads();

    // ---- P1: horizontal up-conv, 8 cols/thread, static polyphase ----
    // group g: zc=8g..8g+7, window w[j] = x[r][2g+1+j] = s_in[r][2g+j]
    for (unsigned e = tid; e < NIR * 39u; e += 320) {
        unsigned r = e / 39u, g = e - r * 39u;
        const float* si = s_in + r * 84 + 2 * g;
        float2 p0 = *(const float2*)(si);
        float2 p1 = *(const float2*)(si + 2);
        float2 p2 = *(const float2*)(si + 4);
        float2 p3 = *(const float2*)(si + 6);
        float w0=p0.x, w1=p0.y, w2=p1.x, w3=p1.y, w4=p2.x, w5=p2.y, w6=p3.x, w7=p3.y;
        float4 a, b;
        a.x = fu[1]*w5+fu[5]*w4+fu[9]*w3 +fu[13]*w2+fu[17]*w1+fu[21]*w0;
        a.y = fu[2]*w5+fu[6]*w4+fu[10]*w3+fu[14]*w2+fu[18]*w1+fu[22]*w0;
        a.z = fu[3]*w5+fu[7]*w4+fu[11]*w3+fu[15]*w2+fu[19]*w1+fu[23]*w0;
        a.w = fu[0]*w6+fu[4]*w5+fu[8]*w4 +fu[12]*w3+fu[16]*w2+fu[20]*w1;
        b.x = fu[1]*w6+fu[5]*w5+fu[9]*w4 +fu[13]*w3+fu[17]*w2+fu[21]*w1;
        b.y = fu[2]*w6+fu[6]*w5+fu[10]*w4+fu[14]*w3+fu[18]*w2+fu[22]*w1;
        b.z = fu[3]*w6+fu[7]*w5+fu[11]*w4+fu[15]*w3+fu[19]*w2+fu[23]*w1;
        b.w = fu[0]*w7+fu[4]*w6+fu[8]*w5 +fu[12]*w4+fu[16]*w3+fu[20]*w2;
        unsigned colp = 8 * g + ((g >> 2) << 2);   // skew(8g)
        float* dst = s_uph + r * STR + colp;
        *(float4*)(dst)     = a;
        *(float4*)(dst + 4) = b;
    }
    __syncthreads();

    // ---- P2: per-column vertical up + lrelu + down-v into registers ----
    {
        const int zc   = tid < NCOL ? tid : NCOL - 1;
        const int colp = zc + ((zc >> 5) << 2);
        const float* up = s_uph + colp;
        float acc[NROWS];
#pragma unroll
        for (int i = 0; i < NROWS; ++i) acc[i] = 0.0f;
        float w0 = up[0*STR], w1 = up[1*STR], w2 = up[2*STR],
              w3 = up[3*STR], w4 = up[4*STR], w5 = up[5*STR];
#pragma unroll
        for (int s = 0; s < NZR; ++s) {
            if ((s & 3) == 3) {                     // window advance (ph->0)
                w0=w1; w1=w2; w2=w3; w3=w4; w4=w5;
                w5 = up[(6 + (s >> 2)) * STR];
            }
            const int ph = (s + 1) & 3;
            float z = fu[ph]*w5 + fu[ph+4]*w4 + fu[ph+8]*w3
                    + fu[ph+12]*w2 + fu[ph+16]*w1 + fu[ph+20]*w0;
            z = z > 0.0f ? z : SLOPE * z;
            const int m = s >> 1;
#pragma unroll
            for (int k = 0; k < 6; ++k) {           // static after unroll
                const int li = m - k;
                if (li >= 0 && li < NROWS)
                    acc[li] += z * fd[(s & 1) ? (10 - 2*k) : (11 - 2*k)];
            }
        }
        __syncthreads();            // all uph reads complete
        if (tid < NCOL) {
            float* tvc = s_tv + colp;
#pragma unroll
            for (int i = 0; i < NROWS; ++i) tvc[i * STR] = acc[i];
        }
    }
    __syncthreads();

    // ---- P3: horizontal down-conv + store, 8 out cols/thread ----
    for (unsigned e = tid; e < NROWS * 19u; e += 320) {
        unsigned i = e / 19u, g8 = e - i * 19u;
        float W[28];
#pragma unroll
        for (int k = 0; k < 7; ++k) {
            int ck = 16 * (int)g8 + 4 * k;
            int cp = ck + ((ck >> 5) << 2);         // skew
            float4 v = *(const float4*)(s_tv + i * STR + cp);
            W[4*k+0]=v.x; W[4*k+1]=v.y; W[4*k+2]=v.z; W[4*k+3]=v.w;
        }
        float ov[8];
#pragma unroll
        for (int m = 0; m < 8; ++m) {
            float s = 0.0f;
#pragma unroll
            for (int u = 0; u < 12; ++u) s += fd[u] * W[2*m + 11 - u];
            ov[m] = s;
        }
        float* orow = o + (size_t)(i0 + i) * OUT_HW + 8 * g8;
        *(float4*)(orow) = make_float4(ov[0], ov[1], ov[2], ov[3]);
        if (g8 < 18) *(float4*)(orow + 4) = make_float4(ov[4], ov[5], ov[6], ov[7]);
    }
}

__global__ __launch_bounds__(320, 4) void afa_band(
    const float* __restrict__ x, const float* __restrict__ ku,
    const float* __restrict__ kd, float* __restrict__ out)
{
    __shared__ float sbuf[LDS_DW];
    const int tid  = threadIdx.x;
    const int band = blockIdx.x;     // 0..4
    const int pz   = blockIdx.y;     // 0..511
    float fu[24], fd[12];
#pragma unroll
    for (int i = 0; i < 24; ++i) fu[i] = rfl(ku[i]);
#pragma unroll
    for (int i = 0; i < 12; ++i) fd[i] = rfl(kd[i]);
    const float* xin = x + (size_t)pz * IN_HW * IN_HW;
    float* o = out + (size_t)pz * OUT_HW * OUT_HW;
    if (band < 4) band_body<32, 74, 24>(xin, o, fu, fd, sbuf, tid, band);
    else          band_body<20, 50, 18>(xin, o, fu, fd, sbuf, tid, band);
}

extern "C" void kernel_launch(void* const* d_in, const int* in_sizes, int n_in,
                              void* d_out, int out_size, void* d_ws, size_t ws_size,
                              hipStream_t stream) {
    const float* x  = (const float*)d_in[0];
    const float* ku = (const float*)d_in[1];
    const float* kd = (const float*)d_in[2];
    float* out = (float*)d_out;
    dim3 grid(5, 512);
    afa_band<<<grid, dim3(320), 0, stream>>>(x, ku, kd, out);
}

// Round 4
// 68.877 us; speedup vs baseline: 1.1794x; 1.1794x over previous
//
#include <hip/hip_runtime.h>

// AliasFreeActivation, round 4: column-fused 16-row bands, register-preloaded columns.
// x (2,256,84,84) f32 -> up x4 (24t sep) -> lrelu -> down x2 (12t sep) -> crop 10
// out (2,256,148,148) f32.
//
// Band b (10 bands/plane): out rows i0..i0+15, i0 = min(16b, 132) (band 9 overlaps
// band 8 by 12 rows; values bitwise-identical, duplicate stores safe).
// z rows ZR0=2*i0+15 (always ≡3 mod 4), 42 steps; z cols 15..320 (306 local cols).
// Input rows IR0=i0/2+1 .. +15 — always in-bounds, no guards anywhere.
// P2: one thread per z-column; preload 16-row uph column into regs, then fully
// unrolled up-v + lrelu + down-v accumulation into 16 reg accumulators (no LDS
// on the dependent path). tv buffer aliases in+uph after a barrier.

constexpr int IN_HW  = 84;
constexpr int OUT_HW = 148;
constexpr int NCOL   = 306;           // local z columns (z col = 15 + zc)
constexpr int STR    = 356;           // skewed col stride (dwords)
constexpr int NROWS  = 16;            // out rows per band
constexpr int NZR    = 2 * NROWS + 10;   // 42 z rows per band
constexpr int NIR    = 16;            // staged input / uph rows per band
constexpr int IN_STR = 84;
constexpr int UPH_OFF = NIR * IN_STR;           // 1344 dw
constexpr int LDS_DW  = UPH_OFF + NIR * STR;    // 7040 dw = 28160 B
constexpr float SLOPE = 0.2f;

__device__ __forceinline__ float rfl(float v) {
    return __uint_as_float(__builtin_amdgcn_readfirstlane(__float_as_uint(v)));
}

__global__ __launch_bounds__(320, 6) void afa_band(
    const float* __restrict__ x, const float* __restrict__ ku,
    const float* __restrict__ kd, float* __restrict__ out)
{
    __shared__ float sbuf[LDS_DW];
    float* s_in  = sbuf;              // [NIR][84], cols = x cols 1..82
    float* s_uph = sbuf + UPH_OFF;    // [NIR][STR], skewed cols
    float* s_tv  = sbuf;              // [NROWS][STR], aliases in+uph post-barrier

    const int tid  = threadIdx.x;
    const int band = blockIdx.x;      // 0..9
    const int pz   = blockIdx.y;      // 0..511
    const int i0   = (band == 9) ? 132 : 16 * band;
    const int IR0  = (i0 >> 1) + 1;

    float fu[24], fd[12];
#pragma unroll
    for (int i = 0; i < 24; ++i) fu[i] = rfl(ku[i]);
#pragma unroll
    for (int i = 0; i < 12; ++i) fd[i] = rfl(kd[i]);

    const float* xin = x + (size_t)pz * IN_HW * IN_HW;
    float* o = out + (size_t)pz * OUT_HW * OUT_HW;

    // ---- P0: stage input rows IR0..IR0+15, cols 1..82 (always in-bounds) ----
    for (int e = tid; e < NIR * 82; e += 320) {
        int r = e / 82, c = e - r * 82;
        s_in[r * IN_STR + c] = xin[(IR0 + r) * IN_HW + 1 + c];
    }
    __syncthreads();

    // ---- P1: horizontal up-conv, 8 z-cols per task, static polyphase ----
    for (int e = tid; e < NIR * 39; e += 320) {
        int r = e / 39, g = e - r * 39;
        const float* si = s_in + r * IN_STR + 2 * g;
        float2 p0 = *(const float2*)(si);
        float2 p1 = *(const float2*)(si + 2);
        float2 p2 = *(const float2*)(si + 4);
        float2 p3 = *(const float2*)(si + 6);
        float w0=p0.x, w1=p0.y, w2=p1.x, w3=p1.y, w4=p2.x, w5=p2.y, w6=p3.x, w7=p3.y;
        float4 a, b;
        a.x = fu[1]*w5+fu[5]*w4+fu[9]*w3 +fu[13]*w2+fu[17]*w1+fu[21]*w0;
        a.y = fu[2]*w5+fu[6]*w4+fu[10]*w3+fu[14]*w2+fu[18]*w1+fu[22]*w0;
        a.z = fu[3]*w5+fu[7]*w4+fu[11]*w3+fu[15]*w2+fu[19]*w1+fu[23]*w0;
        a.w = fu[0]*w6+fu[4]*w5+fu[8]*w4 +fu[12]*w3+fu[16]*w2+fu[20]*w1;
        b.x = fu[1]*w6+fu[5]*w5+fu[9]*w4 +fu[13]*w3+fu[17]*w2+fu[21]*w1;
        b.y = fu[2]*w6+fu[6]*w5+fu[10]*w4+fu[14]*w3+fu[18]*w2+fu[22]*w1;
        b.z = fu[3]*w6+fu[7]*w5+fu[11]*w4+fu[15]*w3+fu[19]*w2+fu[23]*w1;
        b.w = fu[0]*w7+fu[4]*w6+fu[8]*w5 +fu[12]*w4+fu[16]*w3+fu[20]*w2;
        int colp = 8 * g + ((g >> 2) << 2);     // skew(8g)
        float* dst = s_uph + r * STR + colp;
        *(float4*)(dst)     = a;
        *(float4*)(dst + 4) = b;
    }
    __syncthreads();

    // ---- P2: per-column vertical up + lrelu + down-v, all in registers ----
    float acc[NROWS];
    {
        const int zc   = tid < NCOL ? tid : NCOL - 1;
        const int colp = zc + ((zc >> 5) << 2);
        const float* up = s_uph + colp;
        float colv[NIR];
#pragma unroll
        for (int r = 0; r < NIR; ++r) colv[r] = up[r * STR];   // independent loads
#pragma unroll
        for (int i = 0; i < NROWS; ++i) acc[i] = 0.0f;
#pragma unroll
        for (int s = 0; s < NZR; ++s) {
            const int n  = (s + 1) >> 2;
            const int ph = (s + 1) & 3;
            float z = fu[ph]*colv[n+5] + fu[ph+4]*colv[n+4] + fu[ph+8]*colv[n+3]
                    + fu[ph+12]*colv[n+2] + fu[ph+16]*colv[n+1] + fu[ph+20]*colv[n];
            z = z > 0.0f ? z : SLOPE * z;
            const int m = s >> 1;
#pragma unroll
            for (int k = 0; k < 6; ++k) {         // static after unroll
                const int li = m - k;
                if (li >= 0 && li < NROWS)
                    acc[li] += z * fd[(s & 1) ? (10 - 2*k) : (11 - 2*k)];
            }
        }
        __syncthreads();                // all P2 LDS reads done before aliasing
        if (tid < NCOL) {
            float* tvc = s_tv + colp;
#pragma unroll
            for (int i = 0; i < NROWS; ++i) tvc[i * STR] = acc[i];
        }
    }
    __syncthreads();

    // ---- P3: horizontal down-conv + store, 8 out cols per task ----
    for (int e = tid; e < NROWS * 19; e += 320) {
        int i = e / 19, g8 = e - i * 19;
        float W[28];
#pragma unroll
        for (int k = 0; k < 7; ++k) {
            int ck = 16 * g8 + 4 * k;
            int cp = ck + ((ck >> 5) << 2);       // skew
            float4 v = *(const float4*)(s_tv + i * STR + cp);
            W[4*k+0]=v.x; W[4*k+1]=v.y; W[4*k+2]=v.z; W[4*k+3]=v.w;
        }
        float ov[8];
#pragma unroll
        for (int m = 0; m < 8; ++m) {
            float s = 0.0f;
#pragma unroll
            for (int u = 0; u < 12; ++u) s += fd[u] * W[2*m + 11 - u];
            ov[m] = s;
        }
        float* orow = o + (size_t)(i0 + i) * OUT_HW + 8 * g8;
        *(float4*)(orow) = make_float4(ov[0], ov[1], ov[2], ov[3]);
        if (g8 < 18) *(float4*)(orow + 4) = make_float4(ov[4], ov[5], ov[6], ov[7]);
    }
}

extern "C" void kernel_launch(void* const* d_in, const int* in_sizes, int n_in,
                              void* d_out, int out_size, void* d_ws, size_t ws_size,
                              hipStream_t stream) {
    const float* x  = (const float*)d_in[0];
    const float* ku = (const float*)d_in[1];
    const float* kd = (const float*)d_in[2];
    float* out = (float*)d_out;
    dim3 grid(10, 512);
    afa_band<<<grid, dim3(320), 0, stream>>>(x, ku, kd, out);
}

// Round 5
// 64.950 us; speedup vs baseline: 1.2507x; 1.0605x over previous
//
#include <hip/hip_runtime.h>

// AliasFreeActivation, round 5: 640-thread blocks = 2 planes/block, no s_in,
// 3 barriers. x (2,256,84,84) f32 -> up x4 (24t) -> lrelu -> down x2 (12t)
// -> crop 10 -> out (2,256,148,148) f32.
//
// Band b (10/plane): out rows i0..i0+15, i0 = min(16b,132) (band 9 overlaps
// band 8; duplicate stores bitwise-identical). z rows ZR0=2*i0+15 (≡3 mod 4),
// 42 steps; z cols 15..320 (306 local). Input rows IR0=i0/2+1..+15, always
// in-bounds. Each 320-thread half handles one plane; halves share barriers.
// P1: direct global->reg window reads (plane is cache-resident), up-h -> LDS.
// P2: thread-per-column, register-preloaded column, fused up-v+lrelu+down-v.
// tv aliases uph after a barrier.

constexpr int IN_HW  = 84;
constexpr int OUT_HW = 148;
constexpr int NCOL   = 306;          // local z columns (z col = 15+zc)
constexpr int STR    = 356;          // skewed col stride (dwords)
constexpr int NROWS  = 16;           // out rows per band
constexpr int NZR    = 42;           // z rows per band
constexpr int NIR    = 16;           // uph rows per band
constexpr int HALF_DW = NIR * STR;   // 5696 dw = 22784 B per half
constexpr float SLOPE = 0.2f;

__device__ __forceinline__ float rfl(float v) {
    return __uint_as_float(__builtin_amdgcn_readfirstlane(__float_as_uint(v)));
}

__global__ __launch_bounds__(640, 7) void afa_band(
    const float* __restrict__ x, const float* __restrict__ ku,
    const float* __restrict__ kd, float* __restrict__ out)
{
    __shared__ float sbuf[2 * HALF_DW];          // 45568 B
    const int tid  = threadIdx.x;
    const int h    = tid >= 320;
    const int lt   = tid - (h ? 320 : 0);
    const int band = blockIdx.x;                 // 0..9
    const int pz   = 2 * blockIdx.y + h;         // 0..511
    const int i0   = (band == 9) ? 132 : 16 * band;
    const int IR0  = (i0 >> 1) + 1;

    float* s_uph = sbuf + h * HALF_DW;           // [NIR][STR] skewed
    float* s_tv  = s_uph;                        // aliases (post-barrier)

    float fu[24], fd[12];
#pragma unroll
    for (int i = 0; i < 24; ++i) fu[i] = rfl(ku[i]);
#pragma unroll
    for (int i = 0; i < 12; ++i) fd[i] = rfl(kd[i]);

    const float* xin = x + (size_t)pz * (IN_HW * IN_HW);
    float* o = out + (size_t)pz * (OUT_HW * OUT_HW);

    // ---- P1: horizontal up-conv, global->reg window, 8 z-cols/task ----
    // task (r,g): window w0..w7 = x[IR0+r][2g+1 .. 2g+8]
    for (int e = lt; e < NIR * 39; e += 320) {
        int r = e / 39, g = e - r * 39;
        const float* xr = xin + (IR0 + r) * IN_HW + 2 * g;
        float2 p0 = *(const float2*)(xr);
        float2 p1 = *(const float2*)(xr + 2);
        float2 p2 = *(const float2*)(xr + 4);
        float2 p3 = *(const float2*)(xr + 6);
        float2 p4 = *(const float2*)(xr + ((g == 38) ? 6 : 8)); // avoid OOB tail
        float w0 = p0.y, w1 = p1.x, w2 = p1.y, w3 = p2.x,
              w4 = p2.y, w5 = p3.x, w6 = p3.y, w7 = p4.x;
        float4 a, b;
        a.x = fu[1]*w5+fu[5]*w4+fu[9]*w3 +fu[13]*w2+fu[17]*w1+fu[21]*w0;
        a.y = fu[2]*w5+fu[6]*w4+fu[10]*w3+fu[14]*w2+fu[18]*w1+fu[22]*w0;
        a.z = fu[3]*w5+fu[7]*w4+fu[11]*w3+fu[15]*w2+fu[19]*w1+fu[23]*w0;
        a.w = fu[0]*w6+fu[4]*w5+fu[8]*w4 +fu[12]*w3+fu[16]*w2+fu[20]*w1;
        b.x = fu[1]*w6+fu[5]*w5+fu[9]*w4 +fu[13]*w3+fu[17]*w2+fu[21]*w1;
        b.y = fu[2]*w6+fu[6]*w5+fu[10]*w4+fu[14]*w3+fu[18]*w2+fu[22]*w1;
        b.z = fu[3]*w6+fu[7]*w5+fu[11]*w4+fu[15]*w3+fu[19]*w2+fu[23]*w1;
        b.w = fu[0]*w7+fu[4]*w6+fu[8]*w5 +fu[12]*w4+fu[16]*w3+fu[20]*w2;
        int colp = 8 * g + ((g >> 2) << 2);      // skew(8g)
        float* dst = s_uph + r * STR + colp;
        *(float4*)(dst)     = a;
        *(float4*)(dst + 4) = b;
    }
    __syncthreads();

    // ---- P2: per-column up-v + lrelu + down-v, all in registers ----
    {
        const int zc   = lt < NCOL ? lt : NCOL - 1;
        const int colp = zc + ((zc >> 5) << 2);
        const float* up = s_uph + colp;
        float colv[NIR];
#pragma unroll
        for (int r = 0; r < NIR; ++r) colv[r] = up[r * STR];
        float acc[NROWS];
#pragma unroll
        for (int i = 0; i < NROWS; ++i) acc[i] = 0.0f;
#pragma unroll
        for (int s = 0; s < NZR; ++s) {
            const int n  = (s + 1) >> 2;
            const int ph = (s + 1) & 3;
            float z = fu[ph]*colv[n+5] + fu[ph+4]*colv[n+4] + fu[ph+8]*colv[n+3]
                    + fu[ph+12]*colv[n+2] + fu[ph+16]*colv[n+1] + fu[ph+20]*colv[n];
            z = z > 0.0f ? z : SLOPE * z;
            const int m = s >> 1;
#pragma unroll
            for (int k = 0; k < 6; ++k) {        // static after unroll
                const int li = m - k;
                if (li >= 0 && li < NROWS)
                    acc[li] += z * fd[(s & 1) ? (10 - 2*k) : (11 - 2*k)];
            }
        }
        __syncthreads();                         // all column reads complete
        if (lt < NCOL) {
            float* tvc = s_tv + colp;
#pragma unroll
            for (int i = 0; i < NROWS; ++i) tvc[i * STR] = acc[i];
        }
    }
    __syncthreads();

    // ---- P3: horizontal down-conv + store, 8 out cols/task ----
    if (lt < NROWS * 19) {
        int i = lt / 19, g8 = lt - i * 19;
        float W[28];
#pragma unroll
        for (int k = 0; k < 7; ++k) {
            int ck = 16 * g8 + 4 * k;
            int cp = ck + ((ck >> 5) << 2);      // skew
            float4 v = *(const float4*)(s_tv + i * STR + cp);
            W[4*k+0]=v.x; W[4*k+1]=v.y; W[4*k+2]=v.z; W[4*k+3]=v.w;
        }
        float ov[8];
#pragma unroll
        for (int m = 0; m < 8; ++m) {
            float s = 0.0f;
#pragma unroll
            for (int u = 0; u < 12; ++u) s += fd[u] * W[2*m + 11 - u];
            ov[m] = s;
        }
        float* orow = o + (size_t)(i0 + i) * OUT_HW + 8 * g8;
        *(float4*)(orow) = make_float4(ov[0], ov[1], ov[2], ov[3]);
        if (g8 < 18) *(float4*)(orow + 4) = make_float4(ov[4], ov[5], ov[6], ov[7]);
    }
}

extern "C" void kernel_launch(void* const* d_in, const int* in_sizes, int n_in,
                              void* d_out, int out_size, void* d_ws, size_t ws_size,
                              hipStream_t stream) {
    const float* x  = (const float*)d_in[0];
    const float* ku = (const float*)d_in[1];
    const float* kd = (const float*)d_in[2];
    float* out = (float*)d_out;
    dim3 grid(10, 256);
    afa_band<<<grid, dim3(640), 0, stream>>>(x, ku, kd, out);
}

// Round 6
// 58.406 us; speedup vs baseline: 1.3909x; 1.1121x over previous
//
#include <hip/hip_runtime.h>

// AliasFreeActivation, round 6: 320-thread single-plane bands, LDS < 20KB
// (occupancy-granule theory), no skew, direct-global P1.
// x (2,256,84,84) f32 -> up x4 (24t) -> lrelu -> down x2 (12t) -> crop 10
// -> out (2,256,148,148) f32.
//
// Band b (10/plane): out rows i0..i0+15, i0 = min(16b,132) (band 9 overlaps
// band 8; duplicate stores bitwise-identical). z rows ZR0=2*i0+15 (≡3 mod 4),
// 42 steps; z cols 15..320 (306 local). Input rows IR0=i0/2+1..+15, in-bounds.
// P1: global->reg window reads (plane L1/L2-resident), up-h -> LDS [16][312].
// P2: thread-per-column, register-preloaded column, fused up-v+lrelu+down-v.
// tv aliases uph after a barrier. P2 column reads are lane-per-column
// (same row, consecutive cols) => bank-conflict-free without skew.

constexpr int IN_HW  = 84;
constexpr int OUT_HW = 148;
constexpr int NCOL   = 306;          // local z columns (z col = 15+zc)
constexpr int STR    = 312;          // col stride (dwords), no skew
constexpr int NROWS  = 16;           // out rows per band
constexpr int NZR    = 42;           // z rows per band
constexpr int NIR    = 16;           // uph rows per band
constexpr int LDS_DW = NIR * STR + 4;   // +4 dw pad for P3 tail b128 reads
constexpr float SLOPE = 0.2f;

__device__ __forceinline__ float rfl(float v) {
    return __uint_as_float(__builtin_amdgcn_readfirstlane(__float_as_uint(v)));
}

__global__ __launch_bounds__(320, 7) void afa_band(
    const float* __restrict__ x, const float* __restrict__ ku,
    const float* __restrict__ kd, float* __restrict__ out)
{
    __shared__ float sbuf[LDS_DW];               // 19984 B
    float* s_uph = sbuf;                         // [NIR][STR]
    float* s_tv  = sbuf;                         // aliases (post-barrier)

    const int lt   = threadIdx.x;
    const int band = blockIdx.x;                 // 0..9
    const int pz   = blockIdx.y;                 // 0..511
    const int i0   = (band == 9) ? 132 : 16 * band;
    const int IR0  = (i0 >> 1) + 1;

    float fu[24], fd[12];
#pragma unroll
    for (int i = 0; i < 24; ++i) fu[i] = rfl(ku[i]);
#pragma unroll
    for (int i = 0; i < 12; ++i) fd[i] = rfl(kd[i]);

    const float* xin = x + (size_t)pz * (IN_HW * IN_HW);
    float* o = out + (size_t)pz * (OUT_HW * OUT_HW);

    // ---- P1: horizontal up-conv, global->reg window, 8 z-cols/task ----
    // task (r,g): window w0..w7 = x[IR0+r][2g+1 .. 2g+8]
    for (int e = lt; e < NIR * 39; e += 320) {
        int r = e / 39, g = e - r * 39;
        const float* xr = xin + (IR0 + r) * IN_HW + 2 * g;
        float2 p0 = *(const float2*)(xr);
        float2 p1 = *(const float2*)(xr + 2);
        float2 p2 = *(const float2*)(xr + 4);
        float2 p3 = *(const float2*)(xr + 6);
        float2 p4 = *(const float2*)(xr + ((g == 38) ? 6 : 8)); // avoid OOB tail
        float w0 = p0.y, w1 = p1.x, w2 = p1.y, w3 = p2.x,
              w4 = p2.y, w5 = p3.x, w6 = p3.y, w7 = p4.x;
        float4 a, b;
        a.x = fu[1]*w5+fu[5]*w4+fu[9]*w3 +fu[13]*w2+fu[17]*w1+fu[21]*w0;
        a.y = fu[2]*w5+fu[6]*w4+fu[10]*w3+fu[14]*w2+fu[18]*w1+fu[22]*w0;
        a.z = fu[3]*w5+fu[7]*w4+fu[11]*w3+fu[15]*w2+fu[19]*w1+fu[23]*w0;
        a.w = fu[0]*w6+fu[4]*w5+fu[8]*w4 +fu[12]*w3+fu[16]*w2+fu[20]*w1;
        b.x = fu[1]*w6+fu[5]*w5+fu[9]*w4 +fu[13]*w3+fu[17]*w2+fu[21]*w1;
        b.y = fu[2]*w6+fu[6]*w5+fu[10]*w4+fu[14]*w3+fu[18]*w2+fu[22]*w1;
        b.z = fu[3]*w6+fu[7]*w5+fu[11]*w4+fu[15]*w3+fu[19]*w2+fu[23]*w1;
        b.w = fu[0]*w7+fu[4]*w6+fu[8]*w5 +fu[12]*w4+fu[16]*w3+fu[20]*w2;
        float* dst = s_uph + r * STR + 8 * g;
        *(float4*)(dst)     = a;
        *(float4*)(dst + 4) = b;
    }
    __syncthreads();

    // ---- P2: per-column up-v + lrelu + down-v, all in registers ----
    {
        const int zc  = lt < NCOL ? lt : NCOL - 1;
        const float* up = s_uph + zc;
        float colv[NIR];
#pragma unroll
        for (int r = 0; r < NIR; ++r) colv[r] = up[r * STR];   // imm-offset reads
        float acc[NROWS];
#pragma unroll
        for (int i = 0; i < NROWS; ++i) acc[i] = 0.0f;
#pragma unroll
        for (int s = 0; s < NZR; ++s) {
            const int n  = (s + 1) >> 2;
            const int ph = (s + 1) & 3;
            float z = fu[ph]*colv[n+5] + fu[ph+4]*colv[n+4] + fu[ph+8]*colv[n+3]
                    + fu[ph+12]*colv[n+2] + fu[ph+16]*colv[n+1] + fu[ph+20]*colv[n];
            z = z > 0.0f ? z : SLOPE * z;
            const int m = s >> 1;
#pragma unroll
            for (int k = 0; k < 6; ++k) {        // static after unroll
                const int li = m - k;
                if (li >= 0 && li < NROWS)
                    acc[li] += z * fd[(s & 1) ? (10 - 2*k) : (11 - 2*k)];
            }
        }
        __syncthreads();                         // all column reads complete
        if (lt < NCOL) {
            float* tvc = s_tv + zc;
#pragma unroll
            for (int i = 0; i < NROWS; ++i) tvc[i * STR] = acc[i];
        }
    }
    __syncthreads();

    // ---- P3: horizontal down-conv + store, 8 out cols/task ----
    if (lt < NROWS * 19) {
        int i = lt / 19, g8 = lt - i * 19;
        float W[28];
#pragma unroll
        for (int k = 0; k < 7; ++k) {
            float4 v = *(const float4*)(s_tv + i * STR + 16 * g8 + 4 * k);
            W[4*k+0]=v.x; W[4*k+1]=v.y; W[4*k+2]=v.z; W[4*k+3]=v.w;
        }
        float ov[8];
#pragma unroll
        for (int m = 0; m < 8; ++m) {
            float s = 0.0f;
#pragma unroll
            for (int u = 0; u < 12; ++u) s += fd[u] * W[2*m + 11 - u];
            ov[m] = s;
        }
        float* orow = o + (size_t)(i0 + i) * OUT_HW + 8 * g8;
        *(float4*)(orow) = make_float4(ov[0], ov[1], ov[2], ov[3]);
        if (g8 < 18) *(float4*)(orow + 4) = make_float4(ov[4], ov[5], ov[6], ov[7]);
    }
}

extern "C" void kernel_launch(void* const* d_in, const int* in_sizes, int n_in,
                              void* d_out, int out_size, void* d_ws, size_t ws_size,
                              hipStream_t stream) {
    const float* x  = (const float*)d_in[0];
    const float* ku = (const float*)d_in[1];
    const float* kd = (const float*)d_in[2];
    float* out = (float*)d_out;
    dim3 grid(10, 512);
    afa_band<<<grid, dim3(320), 0, stream>>>(x, ku, kd, out);
}

// Round 7
// 43.481 us; speedup vs baseline: 1.8683x; 1.3432x over previous
//
#include <hip/hip_runtime.h>

// AliasFreeActivation, round 7: packed-fp32 column-pair P2, 2 planes/block.
// x (2,256,84,84) f32 -> up x4 (24t) -> lrelu -> down x2 (12t) -> crop 10
// -> out (2,256,148,148) f32.
//
// Band b (10/plane): out rows i0..i0+15, i0=min(16b,132) (band 9 overlaps
// band 8; duplicate stores bitwise-identical). z rows ZR0=2*i0+15 (≡3 mod 4),
// 42 steps; z cols 15..320 (306 local). Input rows IR0=i0/2+1..+15, in-bounds.
// Block = 320 threads = two 160-thread groups, one plane each (pz0, pz0+1).
// P1: global->reg up-h (scalar), both planes round-robin -> LDS [16][312]/plane.
// P2: one thread per COLUMN-PAIR; all math in float2 -> v_pk_fma_f32
//     (hipcc -ffp-contract=fast fuses vector mul+add), ds_read_b64 loads.
//     Threads 153..159 of each group duplicate pair 152 (same-value writes).
// P3: per-group horizontal down + store (as r6). tv aliases uph post-barrier.

typedef float v2 __attribute__((ext_vector_type(2)));

constexpr int IN_HW  = 84;
constexpr int OUT_HW = 148;
constexpr int STR    = 312;          // row stride (dwords)
constexpr int NROWS  = 16;           // out rows per band
constexpr int NZR    = 42;           // z rows per band
constexpr int NIR    = 16;           // uph rows per band
constexpr int PLANE_DW = NIR * STR + 4;   // 4996 dw (pad for P3 b128 tail)
constexpr float SLOPE = 0.2f;

__device__ __forceinline__ float rfl(float v) {
    return __uint_as_float(__builtin_amdgcn_readfirstlane(__float_as_uint(v)));
}

__global__ __launch_bounds__(320, 6) void afa_band(
    const float* __restrict__ x, const float* __restrict__ ku,
    const float* __restrict__ kd, float* __restrict__ out)
{
    __shared__ float sbuf[2 * PLANE_DW];         // 39968 B
    const int tid  = threadIdx.x;
    const int band = blockIdx.x;                 // 0..9
    const int pz0  = 2 * blockIdx.y;             // planes pz0, pz0+1
    const int i0   = (band == 9) ? 132 : 16 * band;
    const int IR0  = (i0 >> 1) + 1;

    float fu[24], fd[12];
#pragma unroll
    for (int i = 0; i < 24; ++i) fu[i] = rfl(ku[i]);
#pragma unroll
    for (int i = 0; i < 12; ++i) fd[i] = rfl(kd[i]);

    // ---- P1: horizontal up-conv for BOTH planes, global->reg windows ----
    for (int e = tid; e < 2 * NIR * 39; e += 320) {
        int pl = (e >= NIR * 39);
        int e2 = e - pl * (NIR * 39);
        int r = e2 / 39, g = e2 - 39 * r;
        const float* xr = x + (size_t)(pz0 + pl) * (IN_HW * IN_HW)
                        + (IR0 + r) * IN_HW + 2 * g;
        float2 p0 = *(const float2*)(xr);
        float2 p1 = *(const float2*)(xr + 2);
        float2 p2 = *(const float2*)(xr + 4);
        float2 p3 = *(const float2*)(xr + 6);
        float2 p4 = *(const float2*)(xr + ((g == 38) ? 6 : 8)); // avoid OOB
        float w0 = p0.y, w1 = p1.x, w2 = p1.y, w3 = p2.x,
              w4 = p2.y, w5 = p3.x, w6 = p3.y, w7 = p4.x;
        float4 a, b;
        a.x = fu[1]*w5+fu[5]*w4+fu[9]*w3 +fu[13]*w2+fu[17]*w1+fu[21]*w0;
        a.y = fu[2]*w5+fu[6]*w4+fu[10]*w3+fu[14]*w2+fu[18]*w1+fu[22]*w0;
        a.z = fu[3]*w5+fu[7]*w4+fu[11]*w3+fu[15]*w2+fu[19]*w1+fu[23]*w0;
        a.w = fu[0]*w6+fu[4]*w5+fu[8]*w4 +fu[12]*w3+fu[16]*w2+fu[20]*w1;
        b.x = fu[1]*w6+fu[5]*w5+fu[9]*w4 +fu[13]*w3+fu[17]*w2+fu[21]*w1;
        b.y = fu[2]*w6+fu[6]*w5+fu[10]*w4+fu[14]*w3+fu[18]*w2+fu[22]*w1;
        b.z = fu[3]*w6+fu[7]*w5+fu[11]*w4+fu[15]*w3+fu[19]*w2+fu[23]*w1;
        b.w = fu[0]*w7+fu[4]*w6+fu[8]*w5 +fu[12]*w4+fu[16]*w3+fu[20]*w2;
        float* dst = sbuf + pl * PLANE_DW + r * STR + 8 * g;
        *(float4*)(dst)     = a;
        *(float4*)(dst + 4) = b;
    }
    __syncthreads();

    const int h  = (tid >= 160);
    const int lt = tid - 160 * h;
    float* s_pl = sbuf + h * PLANE_DW;           // this group's plane buffer
    float* o = out + (size_t)(pz0 + h) * (OUT_HW * OUT_HW);

    // ---- P2: per-column-PAIR up-v + lrelu + down-v, all float2/pk ----
    {
        const int pc = lt < 153 ? lt : 152;      // clamp: dup work, same-value writes
        const float* up = s_pl + 2 * pc;
        v2 colv[NIR];
#pragma unroll
        for (int r = 0; r < NIR; ++r) colv[r] = *(const v2*)&up[r * STR];
        v2 acc[NROWS];
#pragma unroll
        for (int i = 0; i < NROWS; ++i) acc[i] = (v2)(0.0f);
#pragma unroll
        for (int s = 0; s < NZR; ++s) {
            const int n  = (s + 1) >> 2;
            const int ph = (s + 1) & 3;
            v2 z = colv[n+5] * fu[ph];
            z += colv[n+4] * fu[ph+4];
            z += colv[n+3] * fu[ph+8];
            z += colv[n+2] * fu[ph+12];
            z += colv[n+1] * fu[ph+16];
            z += colv[n]   * fu[ph+20];
            z = __builtin_elementwise_max(z, z * SLOPE);   // lrelu
            const int m = s >> 1;
#pragma unroll
            for (int k = 0; k < 6; ++k) {           // static after unroll
                const int li = m - k;
                if (li >= 0 && li < NROWS)
                    acc[li] += z * fd[(s & 1) ? (10 - 2*k) : (11 - 2*k)];
            }
        }
        __syncthreads();                            // all colv reads complete
        float* tvc = s_pl + 2 * pc;
#pragma unroll
        for (int i = 0; i < NROWS; ++i)
            *(v2*)&tvc[i * STR] = acc[i];
    }
    __syncthreads();

    // ---- P3: horizontal down-conv + store, 8 out cols/task, per group ----
    for (int e = lt; e < NROWS * 19; e += 160) {
        int i = e / 19, g8 = e - i * 19;
        float W[28];
#pragma unroll
        for (int k = 0; k < 7; ++k) {
            float4 v = *(const float4*)(s_pl + i * STR + 16 * g8 + 4 * k);
            W[4*k+0]=v.x; W[4*k+1]=v.y; W[4*k+2]=v.z; W[4*k+3]=v.w;
        }
        float ov[8];
#pragma unroll
        for (int m = 0; m < 8; ++m) {
            float s = 0.0f;
#pragma unroll
            for (int u = 0; u < 12; ++u) s += fd[u] * W[2*m + 11 - u];
            ov[m] = s;
        }
        float* orow = o + (size_t)(i0 + i) * OUT_HW + 8 * g8;
        *(float4*)(orow) = make_float4(ov[0], ov[1], ov[2], ov[3]);
        if (g8 < 18) *(float4*)(orow + 4) = make_float4(ov[4], ov[5], ov[6], ov[7]);
    }
}

extern "C" void kernel_launch(void* const* d_in, const int* in_sizes, int n_in,
                              void* d_out, int out_size, void* d_ws, size_t ws_size,
                              hipStream_t stream) {
    const float* x  = (const float*)d_in[0];
    const float* ku = (const float*)d_in[1];
    const float* kd = (const float*)d_in[2];
    float* out = (float*)d_out;
    dim3 grid(10, 256);
    afa_band<<<grid, dim3(320), 0, stream>>>(x, ku, kd, out);
}